// Round 15
// baseline (2495.356 us; speedup 1.0000x reference)
//
#include <hip/hip_runtime.h>
#include <hip/hip_bf16.h>

#define TSTEPS 512
#define BATCH  32
#define NIN    512
#define NH     1024
#define BNH    (BATCH * NH)   // 32768

typedef __attribute__((ext_vector_type(8))) short  short8v;
typedef __attribute__((ext_vector_type(4))) float  float4v;
typedef unsigned long long ull;

__device__ __forceinline__ unsigned short f2bf(float f) {
  return __builtin_bit_cast(unsigned short, __float2bfloat16(f));
}
__device__ __forceinline__ float4v mfma16(short8v a, short8v b, float4v c) {
  return __builtin_amdgcn_mfma_f32_16x16x32_bf16(a, b, c, 0, 0, 0);
}

// h state swizzle (8B-atomic-pair layout, R7-proven): element (b,k) at
//   (k>>5)*1024 + (b>>4)*512 + ((k>>2)&1)*256 + ((b&15)|(((k>>3)&3)<<4))*4 + (k&3)
__device__ __forceinline__ int swzh(int b, int k) {
  return (k >> 5) * 1024 + (b >> 4) * 512 + ((k >> 2) & 1) * 256 +
         (((b & 15) | (((k >> 3) & 3) << 4)) << 2) + (k & 3);
}
// x bf16 swizzle (plain 16B layout)
__device__ __forceinline__ int swzx(int b, int k) {
  return (k >> 5) * 1024 + (b >> 4) * 512 +
         (((b & 15) | (((k >> 3) & 3) << 4)) << 3) + (k & 7);
}

// 8-k-iter partial GEMM: A from memory (X16: plain 16B bf16; else scoped 8B
// pairs via LLC), B from registers. acc[mt][nt] over 2 M-tiles x 2 N-tiles.
template<bool X16>
__device__ __forceinline__ void kpart8(const ushort* __restrict__ base, int kgb,
                                       int lane, const short8v (&wreg)[8][2],
                                       float4v (&acc)[2][2]) {
  if constexpr (X16) {
    short8v f[2][8];
#pragma unroll
    for (int mt = 0; mt < 2; ++mt)
#pragma unroll
      for (int q = 0; q < 8; ++q)
        f[mt][q] = *(const short8v*)(base + (size_t)(kgb + q) * 1024 + mt * 512 + lane * 8);
#pragma unroll
    for (int q = 0; q < 8; ++q)
#pragma unroll
      for (int mt = 0; mt < 2; ++mt) {
        acc[mt][0] = mfma16(f[mt][q], wreg[q][0], acc[mt][0]);
        acc[mt][1] = mfma16(f[mt][q], wreg[q][1], acc[mt][1]);
      }
  } else {
    ull lo[2][8], hi[2][8];
#pragma unroll
    for (int mt = 0; mt < 2; ++mt)
#pragma unroll
      for (int q = 0; q < 8; ++q) {
        const ull* p = (const ull*)(base + (size_t)(kgb + q) * 1024 + mt * 512 + lane * 4);
        lo[mt][q] = __hip_atomic_load(p,      __ATOMIC_RELAXED, __HIP_MEMORY_SCOPE_SYSTEM);
        hi[mt][q] = __hip_atomic_load(p + 64, __ATOMIC_RELAXED, __HIP_MEMORY_SCOPE_SYSTEM);
      }
#pragma unroll
    for (int q = 0; q < 8; ++q)
#pragma unroll
      for (int mt = 0; mt < 2; ++mt) {
        union { ull u[2]; short8v v; } cv;
        cv.u[0] = lo[mt][q]; cv.u[1] = hi[mt][q];
        acc[mt][0] = mfma16(cv.v, wreg[q][0], acc[mt][0]);
        acc[mt][1] = mfma16(cv.v, wreg[q][1], acc[mt][1]);
      }
  }
}

// per-wave flag poll with bounded backoff (R15): s_sleep(2) (~128cy) between
// rounds cuts the scoped-load spin storm on the LLC ~20x; worst-case adds
// ~55ns to pickup. R7/R14 spun with no backoff.
__device__ __forceinline__ void wave_poll(const int* __restrict__ flags,
                                          int base, int cnt, int need, int lane) {
  if (need <= 0) return;
  const int* f = flags + (size_t)(base + (lane & (cnt - 1))) * 16;
  while (!__all(__hip_atomic_load(f, __ATOMIC_RELAXED, __HIP_MEMORY_SCOPE_SYSTEM) >= need)) {
    __builtin_amdgcn_s_sleep(2);
  }
  asm volatile("" ::: "memory");
}

// Persistent kernel: 256 WGs x 512 threads (8 waves, 2/SIMD), 1 WG/CU.
// R14 structure (proven 2.49 ms: R7 protocol + zl-36 pad + post-flag out
// store + fully-zeroed flags) with exactly one change: poll backoff.
__global__ __launch_bounds__(512, 2)
void lstm_r15(const float* __restrict__ c0_in,
              const float* __restrict__ W0, const float* __restrict__ b0_,
              const float* __restrict__ W1, const float* __restrict__ b1_,
              const ushort* __restrict__ xbf,
              ushort* __restrict__ ring0,   // [8][BNH] bf16, swizzled
              ushort* __restrict__ ring1,   // [2][BNH] bf16, swizzled
              int* __restrict__ flags,      // 256 producers, stride 16 ints
              float* __restrict__ out) {
  __shared__ float zl[8][32][36];          // per-wave z partials, 36-pad

  const int wg    = blockIdx.x;
  const int tid   = threadIdx.x;
  const int res   = wg & 7;
  const int layer = res >> 2;
  const int rank  = (wg >> 3) * 4 + (res & 3);
  const int j0    = rank * 8;
  const int K     = layer ? (2 * NH) : (NIN + NH);
  const float* W    = layer ? W1 : W0;
  const float* bias = layer ? b1_ : b0_;

  const int wv = tid >> 6, lane = tid & 63;
  const bool kactive = layer ? true : (wv < 6);

  // ---- preload this wave's weight K-slice into registers (once) ----
  short8v wreg[8][2];
  if (kactive) {
    const int wkbase = wv * 256;
#pragma unroll
    for (int q = 0; q < 8; ++q)
#pragma unroll
      for (int nt = 0; nt < 2; ++nt) {
        int n  = nt * 16 + (lane & 15);
        int gr = (n >> 3) * NH + j0 + (n & 7);
        int k  = wkbase + q * 32 + (lane >> 4) * 8;
        const float* p = W + (size_t)gr * K + k;
        float4 f0 = *(const float4*)p;
        float4 f1 = *(const float4*)(p + 4);
        short8v r;
        r[0] = (short)f2bf(f0.x); r[1] = (short)f2bf(f0.y);
        r[2] = (short)f2bf(f0.z); r[3] = (short)f2bf(f0.w);
        r[4] = (short)f2bf(f1.x); r[5] = (short)f2bf(f1.y);
        r[6] = (short)f2bf(f1.z); r[7] = (short)f2bf(f1.w);
        wreg[q][nt] = r;
      }
  } else {
#pragma unroll
    for (int q = 0; q < 8; ++q) { wreg[q][0] = short8v{}; wreg[q][1] = short8v{}; }
  }

  // zero my z slice (idle L0 waves 6,7 leave theirs zero forever)
  for (int i = lane; i < 32 * 36; i += 64) (&zl[wv][0][0])[i] = 0.f;

  // epilogue state (threads 0..255): thread -> (batch bb, col jj)
  const int bb = tid >> 3, jj = tid & 7;
  float c = 0.f, bg0 = 0.f, bg1 = 0.f, bg2 = 0.f, bg3 = 0.f;
  if (tid < 256) {
    bg0 = bias[0 * NH + j0 + jj];
    bg1 = bias[1 * NH + j0 + jj];
    bg2 = bias[2 * NH + j0 + jj];
    bg3 = bias[3 * NH + j0 + jj];
    c   = c0_in[layer * BNH + bb * NH + j0 + jj];
  }

  __syncthreads();

  for (int it = 0; it < TSTEPS; ++it) {
    float4v acc[2][2] = {{{0,0,0,0},{0,0,0,0}},{{0,0,0,0},{0,0,0,0}}};

    if (layer == 0) {
      if (wv < 2) {
        kpart8<true>(xbf + (size_t)it * 16384, 8 * wv, lane, wreg, acc);
      } else if (wv < 6) {
        wave_poll(flags, 32 * (wv - 2), 32, it, lane);              // own layer
        kpart8<false>(ring0 + (size_t)(it & 7) * BNH, 8 * (wv - 2), lane, wreg, acc);
      } else {
        wave_poll(flags, 128 + 64 * (wv - 6), 64, it - 6, lane);    // backpressure
      }
    } else {
      if (wv < 4) {
        wave_poll(flags, 32 * wv, 32, it + 1, lane);                // L0 done step it
        kpart8<false>(ring0 + (size_t)((it + 1) & 7) * BNH, 8 * wv, lane, wreg, acc);
      } else {
        wave_poll(flags, 128 + 32 * (wv - 4), 32, it, lane);        // own layer
        kpart8<false>(ring1 + (size_t)((it + 1) & 1) * BNH, 8 * (wv - 4), lane, wreg, acc);
      }
    }

    if (kactive) {
#pragma unroll
      for (int mt = 0; mt < 2; ++mt)
#pragma unroll
        for (int nt = 0; nt < 2; ++nt)
#pragma unroll
          for (int r = 0; r < 4; ++r)
            zl[wv][mt * 16 + (lane >> 4) * 4 + r][nt * 16 + (lane & 15)] = acc[mt][nt][r];
    }
    __syncthreads();

    float hval = 0.f;
    if (tid < 256) {
      float zg[4];
#pragma unroll
      for (int g = 0; g < 4; ++g) {
        float s = 0.f;
#pragma unroll
        for (int w = 0; w < 8; ++w) s += zl[w][bb][g * 8 + jj];
        zg[g] = s;
      }
      float g1 = 1.f / (1.f + __expf(-(zg[0] + bg0)));
      float g2 = 1.f / (1.f + __expf(-(zg[1] + bg1)));
      float g3 = 1.f / (1.f + __expf(-(zg[2] + bg2)));
      float o  = tanhf(zg[3] + bg3);
      c = c * g1 + o * g2;
      hval = tanhf(c) * g3;
      unsigned short hb = f2bf(hval);
      int so = swzh(bb, j0 + jj);
      if (layer == 0) {
        __hip_atomic_store(&ring0[(size_t)((it + 1) & 7) * BNH + so], hb,
                           __ATOMIC_RELAXED, __HIP_MEMORY_SCOPE_SYSTEM);
      } else {
        __hip_atomic_store(&ring1[(size_t)(it & 1) * BNH + so], hb,
                           __ATOMIC_RELAXED, __HIP_MEMORY_SCOPE_SYSTEM);
      }
    }
    asm volatile("s_waitcnt vmcnt(0)" ::: "memory");   // drain scoped stores
    __syncthreads();
    if (tid == 0) {
      __hip_atomic_store(&flags[(size_t)(layer * 128 + rank) * 16], it + 1,
                         __ATOMIC_RELAXED, __HIP_MEMORY_SCOPE_SYSTEM);
    }
    // out store AFTER the flag: never read on-device, off the critical path
    if (layer == 1 && tid < 256)
      out[(size_t)it * BNH + bb * NH + j0 + jj] = hval;
  }
}

// prep: convert x -> bf16 in fragment order, init ring slots (swizzled),
// zero ALL 4096 flag ints (stride-16 x 256 producers), copy the (h0,c0)
// passthrough tail of the output.
__global__ void prep(const float* __restrict__ x,
                     const float* __restrict__ h0_in, const float* __restrict__ c0_in,
                     ushort* __restrict__ xbf, ushort* __restrict__ ring0,
                     ushort* __restrict__ ring1, int* __restrict__ flags,
                     float* __restrict__ out) {
  int i = blockIdx.x * blockDim.x + threadIdx.x;   // 0 .. T*B*NIN-1
  {
    int t = i >> 14, rem = i & 16383;
    int b = rem >> 9, k = rem & 511;
    xbf[(size_t)t * 16384 + swzx(b, k)] = f2bf(x[i]);
  }
  if (i < BNH) {
    int b = i >> 10, j = i & 1023;
    int so = swzh(b, j);
    __hip_atomic_store(&ring0[so], f2bf(h0_in[i]),                 // h0_{-1}, slot 0
                       __ATOMIC_RELAXED, __HIP_MEMORY_SCOPE_SYSTEM);
    __hip_atomic_store(&ring1[BNH + so], f2bf(h0_in[BNH + i]),     // h1_{-1}, slot 1
                       __ATOMIC_RELAXED, __HIP_MEMORY_SCOPE_SYSTEM);
  }
  if (i < 4096) {   // FULL stride-16 flag range (256 producers x 16 ints)
    __hip_atomic_store(&flags[i], 0, __ATOMIC_RELAXED, __HIP_MEMORY_SCOPE_SYSTEM);
  }
  if (i < 2 * BNH) {
    const size_t TB = (size_t)TSTEPS * BNH;
    out[TB + i]           = h0_in[i];
    out[TB + 2 * BNH + i] = c0_in[i];
  }
}

extern "C" void kernel_launch(void* const* d_in, const int* in_sizes, int n_in,
                              void* d_out, int out_size, void* d_ws, size_t ws_size,
                              hipStream_t stream) {
  const float* x  = (const float*)d_in[0];
  const float* h0 = (const float*)d_in[1];
  const float* c0 = (const float*)d_in[2];
  const float* W0 = (const float*)d_in[3];
  const float* b0 = (const float*)d_in[4];
  const float* W1 = (const float*)d_in[5];
  const float* b1 = (const float*)d_in[6];
  float* out = (float*)d_out;

  ushort* xbf   = (ushort*)d_ws;                              // 16 MiB
  ushort* ring0 = (ushort*)((char*)d_ws + 16777216);          // 512 KiB
  ushort* ring1 = (ushort*)((char*)d_ws + 17301504);          // 128 KiB
  int*    flags = (int*)((char*)d_ws + 17432576);             // 16 KiB

  prep<<<dim3(32768), dim3(256), 0, stream>>>(x, h0, c0, xbf, ring0, ring1, flags, out);

  void* args[] = {(void*)&c0, (void*)&W0, (void*)&b0, (void*)&W1, (void*)&b1,
                  (void*)&xbf, (void*)&ring0, (void*)&ring1, (void*)&flags, (void*)&out};
  (void)hipLaunchCooperativeKernel((const void*)lstm_r15, dim3(256), dim3(512),
                                   args, 0, stream);
}